// Round 1
// baseline (813.367 us; speedup 1.0000x reference)
//
#include <hip/hip_runtime.h>
#include <hip/hip_bf16.h>

#define N_NODES 20000
#define N_EDGES 320000
#define DIM 256
#define H_HEADS 4

typedef _Float16 f16x8 __attribute__((ext_vector_type(8)));
typedef float f32x4v __attribute__((ext_vector_type(4)));

// ---------------- init: convert W to f16 transposed, zero stats ----------------
__global__ void k_init(const float* __restrict__ Wn, const float* __restrict__ We,
                       _Float16* __restrict__ WTn, _Float16* __restrict__ WTe,
                       unsigned int* __restrict__ m_enc, float* __restrict__ s_ws,
                       unsigned int* __restrict__ counts)
{
    int i = blockIdx.x * 256 + threadIdx.x;
    if (i < DIM * DIM) {
        int n = i >> 8, k = i & 255;
        WTn[i] = (_Float16)Wn[k * DIM + n];
        WTe[i] = (_Float16)We[k * DIM + n];
    }
    if (i < N_NODES * H_HEADS) { m_enc[i] = 0u; s_ws[i] = 0.f; }
    if (i < N_NODES + 1) counts[i] = 0u;
}

// ---------------- CSR build ----------------
__global__ void k_hist(const int* __restrict__ dst, unsigned int* __restrict__ counts)
{
    int i = blockIdx.x * 256 + threadIdx.x;
    if (i < N_EDGES) atomicAdd(&counts[dst[i]], 1u);
}

__global__ __launch_bounds__(1024) void k_scan(unsigned int* __restrict__ counts,
                                               unsigned int* __restrict__ cursor)
{
    __shared__ unsigned int buf[1024];
    __shared__ unsigned int carry;
    const int t = threadIdx.x;
    if (t == 0) carry = 0u;
    __syncthreads();
    for (int base = 0; base < N_NODES; base += 1024) {
        int i = base + t;
        unsigned int v = (i < N_NODES) ? counts[i] : 0u;
        buf[t] = v;
        __syncthreads();
        for (int off = 1; off < 1024; off <<= 1) {
            unsigned int add = (t >= off) ? buf[t - off] : 0u;
            __syncthreads();
            buf[t] += add;
            __syncthreads();
        }
        unsigned int incl = buf[t];
        unsigned int c = carry;
        if (i < N_NODES) { counts[i] = c + incl - v; cursor[i] = c + incl - v; }
        __syncthreads();
        if (t == 1023) carry = c + incl;
        __syncthreads();
    }
    if (t == 0) counts[N_NODES] = carry;
}

__global__ void k_scatter(const int* __restrict__ dst, unsigned int* __restrict__ cursor,
                          int* __restrict__ esort)
{
    int i = blockIdx.x * 256 + threadIdx.x;
    if (i < N_EDGES) {
        unsigned int p = atomicAdd(&cursor[dst[i]], 1u);
        esort[p] = i;
    }
}

// ---------------- node projection GEMM: ft = nfeat @ W_node  (f32 out) ----------------
__global__ __launch_bounds__(256) void k_gemm_node(
    const float* __restrict__ A, const _Float16* __restrict__ WT,
    float* __restrict__ C, int M)
{
    __shared__ __align__(16) _Float16 Alds[64][40];
    const int t = threadIdx.x;
    const int m0 = blockIdx.x * 64;
    const int lane = t & 63, w = t >> 6;
    const int q = lane >> 4, c16 = lane & 15;
    const int srow = t >> 2;
    const int skb = (t & 3) * 8;
    f32x4v acc[4][4] = {};

    for (int k0 = 0; k0 < DIM; k0 += 32) {
        int grow = m0 + srow;
        f16x8 h8;
        if (grow < M) {
            const float* gp = A + (size_t)grow * DIM + k0 + skb;
            float4 v0 = *(const float4*)gp;
            float4 v1 = *(const float4*)(gp + 4);
            h8[0]=(_Float16)v0.x; h8[1]=(_Float16)v0.y; h8[2]=(_Float16)v0.z; h8[3]=(_Float16)v0.w;
            h8[4]=(_Float16)v1.x; h8[5]=(_Float16)v1.y; h8[6]=(_Float16)v1.z; h8[7]=(_Float16)v1.w;
        } else {
            h8 = (f16x8)(_Float16)0.f;
        }
        __syncthreads();
        *(f16x8*)&Alds[srow][skb] = h8;
        __syncthreads();

        f16x8 bfr[4], afr[4];
#pragma unroll
        for (int ni = 0; ni < 4; ++ni) {
            int col = (w << 6) + (ni << 4) + c16;
            bfr[ni] = *(const f16x8*)(WT + (size_t)col * DIM + k0 + q * 8);
        }
#pragma unroll
        for (int mi = 0; mi < 4; ++mi)
            afr[mi] = *(const f16x8*)&Alds[c16 + 16 * mi][q * 8];
#pragma unroll
        for (int mi = 0; mi < 4; ++mi)
#pragma unroll
            for (int ni = 0; ni < 4; ++ni)
                acc[mi][ni] = __builtin_amdgcn_mfma_f32_16x16x32_f16(afr[mi], bfr[ni], acc[mi][ni], 0, 0, 0);
    }

#pragma unroll
    for (int mi = 0; mi < 4; ++mi) {
#pragma unroll
        for (int reg = 0; reg < 4; ++reg) {
            int row = m0 + 16 * mi + 4 * q + reg;
            if (row < M) {
#pragma unroll
                for (int ni = 0; ni < 4; ++ni) {
                    int c = (w << 6) + (ni << 4) + c16;
                    C[(size_t)row * DIM + c] = acc[mi][ni][reg];
                }
            }
        }
    }
}

// ---------------- fused edge GEMM: eft, ft_prime (f16), a, segment-max ----------------
__global__ __launch_bounds__(256) void k_gemm_edge(
    const float* __restrict__ efeat, const _Float16* __restrict__ WT,
    const float* __restrict__ ft, const int* __restrict__ src, const int* __restrict__ dst,
    _Float16* __restrict__ ftp, float* __restrict__ a_ws, unsigned int* __restrict__ m_enc)
{
    __shared__ __align__(16) _Float16 Alds[64][40];
    const int t = threadIdx.x;
    const int e0 = blockIdx.x * 64;
    const int lane = t & 63, w = t >> 6;
    const int q = lane >> 4, c16 = lane & 15;
    const int srow = t >> 2;
    const int skb = (t & 3) * 8;
    f32x4v acc[4][4] = {};

    for (int k0 = 0; k0 < DIM; k0 += 32) {
        const float* gp = efeat + (size_t)(e0 + srow) * DIM + k0 + skb;
        float4 v0 = *(const float4*)gp;
        float4 v1 = *(const float4*)(gp + 4);
        f16x8 h8;
        h8[0]=(_Float16)v0.x; h8[1]=(_Float16)v0.y; h8[2]=(_Float16)v0.z; h8[3]=(_Float16)v0.w;
        h8[4]=(_Float16)v1.x; h8[5]=(_Float16)v1.y; h8[6]=(_Float16)v1.z; h8[7]=(_Float16)v1.w;
        __syncthreads();
        *(f16x8*)&Alds[srow][skb] = h8;
        __syncthreads();

        f16x8 bfr[4], afr[4];
#pragma unroll
        for (int ni = 0; ni < 4; ++ni) {
            int col = (w << 6) + (ni << 4) + c16;
            bfr[ni] = *(const f16x8*)(WT + (size_t)col * DIM + k0 + q * 8);
        }
#pragma unroll
        for (int mi = 0; mi < 4; ++mi)
            afr[mi] = *(const f16x8*)&Alds[c16 + 16 * mi][q * 8];
#pragma unroll
        for (int mi = 0; mi < 4; ++mi)
#pragma unroll
            for (int ni = 0; ni < 4; ++ni)
                acc[mi][ni] = __builtin_amdgcn_mfma_f32_16x16x32_f16(afr[mi], bfr[ni], acc[mi][ni], 0, 0, 0);
    }

    // epilogue: ft_prime = eft + ft[src]; a = dot(ft_prime, ft[dst]) per head
#pragma unroll
    for (int mi = 0; mi < 4; ++mi) {
#pragma unroll
        for (int reg = 0; reg < 4; ++reg) {
            int r = 16 * mi + 4 * q + reg;
            int e = e0 + r;
            int se = src[e], de = dst[e];
            float dotp = 0.f;
#pragma unroll
            for (int ni = 0; ni < 4; ++ni) {
                int c = (w << 6) + (ni << 4) + c16;
                float v = acc[mi][ni][reg] + ft[(size_t)se * DIM + c];
                ftp[(size_t)e * DIM + c] = (_Float16)v;
                dotp += v * ft[(size_t)de * DIM + c];
            }
            dotp += __shfl_xor(dotp, 1);
            dotp += __shfl_xor(dotp, 2);
            dotp += __shfl_xor(dotp, 4);
            dotp += __shfl_xor(dotp, 8);
            if (c16 == 0) {
                a_ws[e * H_HEADS + w] = dotp;
                unsigned int u = __float_as_uint(dotp);
                u = (u & 0x80000000u) ? ~u : (u | 0x80000000u);
                atomicMax(&m_enc[de * H_HEADS + w], u);
            }
        }
    }
}

// ---------------- softmax numerator + denominator ----------------
__global__ void k_softmax(const int* __restrict__ dst, const unsigned int* __restrict__ m_enc,
                          float* __restrict__ a_ws, float* __restrict__ s_ws)
{
    int i = blockIdx.x * 256 + threadIdx.x;
    if (i >= N_EDGES * H_HEADS) return;
    int e = i >> 2, h = i & 3;
    int de = dst[e];
    unsigned int u = m_enc[de * H_HEADS + h];
    float m = (u & 0x80000000u) ? __uint_as_float(u & 0x7fffffffu) : __uint_as_float(~u);
    float ex = __expf(a_ws[i] - m);
    a_ws[i] = ex;
    atomicAdd(&s_ws[de * H_HEADS + h], ex);
}

// ---------------- CSR aggregation: out[n,h,f] = sum sa * ft_prime ----------------
__global__ __launch_bounds__(256) void k_agg(
    const unsigned int* __restrict__ offs, const int* __restrict__ esort,
    const float* __restrict__ exv, const float* __restrict__ s_ws,
    const _Float16* __restrict__ ftp, float* __restrict__ out)
{
    int n = blockIdx.x;
    int c = threadIdx.x;
    int h = c >> 6;
    int beg = (int)offs[n], end = (int)offs[n + 1];
    float sv = s_ws[n * H_HEADS + h];
    float inv = (end > beg) ? 0.125f / sv : 0.f;
    float acc = 0.f;
    for (int j = beg; j < end; ++j) {
        int e = esort[j];
        float wgt = exv[e * H_HEADS + h] * inv;
        acc += wgt * (float)ftp[(size_t)e * DIM + c];
    }
    out[(size_t)n * DIM + c] = acc;
}

// ---------------- launch ----------------
extern "C" void kernel_launch(void* const* d_in, const int* in_sizes, int n_in,
                              void* d_out, int out_size, void* d_ws, size_t ws_size,
                              hipStream_t stream)
{
    const float* nfeat = (const float*)d_in[0];
    const float* efeat = (const float*)d_in[1];
    const int* src = (const int*)d_in[2];
    const int* dst = (const int*)d_in[3];
    const float* Wn = (const float*)d_in[4];
    const float* We = (const float*)d_in[5];
    float* out = (float*)d_out;

    char* ws = (char*)d_ws;
    size_t off = 0;
    auto alloc = [&](size_t bytes) -> void* {
        off = (off + 255) & ~(size_t)255;
        void* p = ws + off;
        off += bytes;
        return p;
    };

    _Float16* WTn = (_Float16*)alloc((size_t)DIM * DIM * 2);
    _Float16* WTe = (_Float16*)alloc((size_t)DIM * DIM * 2);
    float* ft = (float*)alloc((size_t)N_NODES * DIM * 4);
    _Float16* ftp = (_Float16*)alloc((size_t)N_EDGES * DIM * 2);
    float* a_ws = (float*)alloc((size_t)N_EDGES * H_HEADS * 4);
    unsigned int* m_enc = (unsigned int*)alloc((size_t)N_NODES * H_HEADS * 4);
    float* s_ws = (float*)alloc((size_t)N_NODES * H_HEADS * 4);
    unsigned int* counts = (unsigned int*)alloc((size_t)(N_NODES + 1) * 4);
    unsigned int* cursor = (unsigned int*)alloc((size_t)N_NODES * 4);
    int* esort = (int*)alloc((size_t)N_EDGES * 4);

    k_init<<<320, 256, 0, stream>>>(Wn, We, WTn, WTe, m_enc, s_ws, counts);
    k_hist<<<(N_EDGES + 255) / 256, 256, 0, stream>>>(dst, counts);
    k_scan<<<1, 1024, 0, stream>>>(counts, cursor);
    k_scatter<<<(N_EDGES + 255) / 256, 256, 0, stream>>>(dst, cursor, esort);
    k_gemm_node<<<(N_NODES + 63) / 64, 256, 0, stream>>>(nfeat, WTn, ft, N_NODES);
    k_gemm_edge<<<N_EDGES / 64, 256, 0, stream>>>(efeat, WTe, ft, src, dst, ftp, a_ws, m_enc);
    k_softmax<<<(N_EDGES * H_HEADS + 255) / 256, 256, 0, stream>>>(dst, m_enc, a_ws, s_ws);
    k_agg<<<N_NODES, 256, 0, stream>>>(counts, esort, a_ws, s_ws, ftp, out);
}